// Round 22
// baseline (525.867 us; speedup 1.0000x reference)
//
#include <hip/hip_runtime.h>
#include <hip/hip_bf16.h>

typedef __attribute__((ext_vector_type(8))) short short8v;
typedef __attribute__((ext_vector_type(8))) unsigned short ushort8v;
typedef __attribute__((ext_vector_type(8))) _Float16 half8v;
typedef __attribute__((ext_vector_type(4))) float f32x4;

static constexpr int BN = 2;
static constexpr int H0 = 480, W0 = 640;
static constexpr int HW1 = H0 * W0;

struct MSD {
    int s0[4], s1[4];                 // block-range starts (conv0 / convmm grids), [3]=total
    int hs[3], ws[3];
    int tx0[3], tx1[3];
    unsigned long long xp8[3];        // xpad region offsets (shorts)
    unsigned long long x64[3];        // pad region offsets (shorts)
    unsigned long long pxo[3];        // pixel offsets (px, both batches)
};

__device__ __forceinline__ unsigned short f2h(float f) {
    _Float16 h = (_Float16)f;
    unsigned short s; __builtin_memcpy(&s, &h, 2); return s;
}
__device__ __forceinline__ float h2f(unsigned short s) {
    _Float16 h; __builtin_memcpy(&h, &s, 2); return (float)h;
}

// raw barrier: lgkmcnt(0) for cross-wave LDS visibility; vmcnt stays counted
__device__ __forceinline__ void wave_barrier() {
    asm volatile("s_waitcnt lgkmcnt(0)" ::: "memory");
    __builtin_amdgcn_sched_barrier(0);
    __builtin_amdgcn_s_barrier();
}

// ---------------- MFMA weight transform (64->64) fp16 ----------------
__global__ void wtr2_k(const float* __restrict__ w, short* __restrict__ WB) {
    int gid = blockIdx.x * 256 + threadIdx.x;
    if (gid >= 18 * 4 * 512) return;
    int ie = gid & 7;
    int l  = (gid >> 3) & 63;
    int n  = (gid >> 9) & 3;
    int t2 = gid >> 11;            // 0..17
    int tap = t2 >> 1, ks = t2 & 1;
    int o = 16 * n + (l & 15);
    int c = 32 * ks + (l >> 4) * 8 + ie;
    WB[gid] = (short)f2h(w[(size_t)(o * 64 + c) * 9 + tap]);
}

// ---------------- conv0 MFMA weight transform fp16 ----------------
__global__ void wtr0_k(const float* __restrict__ w, short* __restrict__ WB) {
    int gid = blockIdx.x * 256 + threadIdx.x;
    if (gid >= 3 * 4 * 512) return;
    int ie = gid & 7;
    int l  = (gid >> 3) & 63;
    int n  = (gid >> 9) & 3;
    int j  = gid >> 11;            // 0..2
    int o = 16 * n + (l & 15);
    int g = l >> 4;
    int tap = 4 * j + g;
    float wv = (tap < 9 && ie < 6) ? w[(size_t)(o * 6 + ie) * 9 + tap] : 0.f;
    WB[gid] = (short)f2h(wv);
}

// ---------------- head weight transform fp16 ----------------
__global__ void whb_k(const float* __restrict__ wa, const float* __restrict__ wg,
                      const float* __restrict__ wc, short* __restrict__ WB) {
    int gid = blockIdx.x * 256 + threadIdx.x;
    if (gid >= 18 * 2 * 512) return;
    int ie = gid & 7;
    int l  = (gid >> 3) & 63;
    int n  = (gid >> 9) & 1;
    int t2 = gid >> 10;            // 0..17
    int tap = t2 >> 1, ks = t2 & 1;
    int o = 16 * n + (l & 15);
    int c = 32 * ks + (l >> 4) * 8 + ie;
    float wv = 0.f;
    if (o < 24)                 wv = wa[(size_t)(o * 64 + c) * 9 + tap];
    else if (o >= 24 && o < 27) wv = wg[(size_t)((o - 24) * 64 + c) * 9 + tap];
    else if (o >= 28 && o < 31) wv = wc[(size_t)((o - 28) * 65 + c) * 9 + tap];
    WB[gid] = (short)f2h(wv);
}

__global__ void hbias_k(const float* __restrict__ ba, const float* __restrict__ bg,
                        const float* __restrict__ bc, float* __restrict__ hb) {
    int o = threadIdx.x;
    if (o >= 32) return;
    float v = 0.f;
    if (o < 24) v = ba[o];
    else if (o < 27) v = bg[o - 24];
    else if (o >= 28 && o < 31) v = bc[o - 28];
    hb[o] = v;
}

// ---------------- fused per-scale prep ----------------
template <int F>
__global__ void prep_k(const float* __restrict__ I, const float* __restrict__ DL,
                       const float* __restrict__ ML, const float* __restrict__ E,
                       short* __restrict__ Xp, float* __restrict__ Ebuf,
                       float* __restrict__ dlm, int Hs, int Ws) {
    const int pw = Ws + 2;
    int gid = blockIdx.x * 256 + threadIdx.x;
    int total = BN * (Hs + 2) * pw;
    if (gid >= total) return;
    int xp = gid % pw;
    int yp = (gid / pw) % (Hs + 2);
    int b = gid / (pw * (Hs + 2));
    short8v v = {0, 0, 0, 0, 0, 0, 0, 0};
    if (yp >= 1 && yp <= Hs && xp >= 1 && xp <= Ws) {
        int oy = yp - 1, ox = xp - 1;
        if constexpr (F == 1) {
            int p = oy * W0 + ox;
#pragma unroll
            for (int c = 0; c < 3; c++)
                v[c] = (short)f2h(I[(size_t)(b * 3 + c) * HW1 + p]);
            float e = fminf(fmaxf(E[(size_t)b * HW1 + p], 0.f), 1.f);
            v[5] = (short)f2h(e);
            Ebuf[(size_t)b * Hs * Ws + p] = e;
            float m = ML[(size_t)b * HW1 + p] > 0.f ? 1.f : 0.f;
            float s = DL[(size_t)b * HW1 + p] * m;
            float dls = m > 0.f ? s / (m + 1e-6f) : 0.f;
            v[3] = (short)f2h(dls);
            v[4] = (short)f2h(m);
            dlm[(size_t)b * Hs * Ws + p] = m > 0.f ? dls : -1.f;
        } else {
            constexpr int NT = 2 * F;
            float wy[NT], wx[NT];
            float sy = (oy + 0.5f) * F - 0.5f;
            int jly = F * oy - (F + 1) / 2;
            float wys = 0.f;
#pragma unroll
            for (int t = 0; t < NT; t++) {
                int j = jly + t;
                float w = fmaxf(1.f - fabsf(sy - (float)j) / (float)F, 0.f);
                if (j < 0 || j >= H0) w = 0.f;
                wy[t] = w; wys += w;
            }
            float sx = (ox + 0.5f) * F - 0.5f;
            int jlx = F * ox - (F + 1) / 2;
            float wxs = 0.f;
#pragma unroll
            for (int t = 0; t < NT; t++) {
                int j = jlx + t;
                float w = fmaxf(1.f - fabsf(sx - (float)j) / (float)F, 0.f);
                if (j < 0 || j >= W0) w = 0.f;
                wx[t] = w; wxs += w;
            }
            float inv = 1.f / (wys * wxs);
#pragma unroll
            for (int c = 0; c < 3; c++) {
                const float* ip = I + (size_t)(b * 3 + c) * HW1;
                float acc = 0.f;
#pragma unroll
                for (int ty = 0; ty < NT; ty++) {
                    if (wy[ty] == 0.f) continue;
                    const float* row = ip + (size_t)(jly + ty) * W0;
                    float r = 0.f;
#pragma unroll
                    for (int tx = 0; tx < NT; tx++)
                        if (wx[tx] != 0.f) r += wx[tx] * row[jlx + tx];
                    acc += wy[ty] * r;
                }
                v[c] = (short)f2h(acc * inv);
            }
            {
                const float* ip = E + (size_t)b * HW1;
                float acc = 0.f;
#pragma unroll
                for (int ty = 0; ty < NT; ty++) {
                    if (wy[ty] == 0.f) continue;
                    const float* row = ip + (size_t)(jly + ty) * W0;
                    float r = 0.f;
#pragma unroll
                    for (int tx = 0; tx < NT; tx++)
                        if (wx[tx] != 0.f) r += wx[tx] * row[jlx + tx];
                    acc += wy[ty] * r;
                }
                acc = fminf(fmaxf(acc * inv, 0.f), 1.f);
                v[5] = (short)f2h(acc);
                Ebuf[(size_t)b * Hs * Ws + oy * Ws + ox] = acc;
            }
            {
                float s = 0.f, c = 0.f;
#pragma unroll
                for (int dy = 0; dy < F; dy++)
#pragma unroll
                    for (int dx = 0; dx < F; dx++) {
                        size_t idx = ((size_t)b * H0 + (oy * F + dy)) * W0 + (ox * F + dx);
                        float m = ML[idx] > 0.f ? 1.f : 0.f;
                        s += DL[idx] * m;
                        c += m;
                    }
                float dls = c > 0.f ? s / (c + 1e-6f) : 0.f;
                v[3] = (short)f2h(dls);
                v[4] = (short)f2h(c > 0.f ? 1.f : 0.f);
                dlm[(size_t)b * Hs * Ws + oy * Ws + ox] = c > 0.f ? dls : -1.f;
            }
        }
    }
    *(short8v*)(Xp + (((size_t)b * (Hs + 6) + 2 + yp) * pw + xp) * 8) = v;
}

// ---------------- D init, first scale ----------------
__global__ void dinit_first_k(const float* __restrict__ Ebuf, float* __restrict__ D0,
                              int Hs, int Ws) {
    int gid = blockIdx.x * 256 + threadIdx.x;
    int HW = Hs * Ws;
    if (gid >= BN * HW) return;
    float e = Ebuf[gid];
    D0[gid] = fminf(fmaxf(e * 10.f, 0.f), 10.f);
}

// ---------------- D init, later scales ----------------
__global__ void dinit_blend_k(const float* __restrict__ Dp, const float* __restrict__ Ebuf,
                              float* __restrict__ D0, int Hs, int Ws) {
    int gid = blockIdx.x * 256 + threadIdx.x;
    int HW = Hs * Ws;
    if (gid >= BN * HW) return;
    int ox = gid % Ws;
    int oy = (gid / Ws) % Hs;
    int b = gid / HW;
    int hp = Hs / 2, wp = Ws / 2;
    const float* P = Dp + (size_t)b * hp * wp;

    float ty = 0.5f * oy - 0.25f;
    int jy = (int)floorf(ty);
    float fy = ty - jy;
    float wy0 = 1.f - fy, wy1 = fy;
    bool v0 = (jy >= 0) && (jy < hp);
    bool v1 = (jy + 1 >= 0) && (jy + 1 < hp);
    if (!v0) wy0 = 0.f;
    if (!v1) wy1 = 0.f;
    float wys = wy0 + wy1;

    float tx = 0.5f * ox - 0.25f;
    int jx = (int)floorf(tx);
    float fx = tx - jx;
    float wx0 = 1.f - fx, wx1 = fx;
    bool u0 = (jx >= 0) && (jx < wp);
    bool u1 = (jx + 1 >= 0) && (jx + 1 < wp);
    if (!u0) wx0 = 0.f;
    if (!u1) wx1 = 0.f;
    float wxs = wx0 + wx1;

    int jy0c = v0 ? jy : 0, jy1c = v1 ? (jy + 1) : 0;
    int jx0c = u0 ? jx : 0, jx1c = u1 ? (jx + 1) : 0;
    float up = wy0 * (wx0 * P[(size_t)jy0c * wp + jx0c] + wx1 * P[(size_t)jy0c * wp + jx1c])
             + wy1 * (wx0 * P[(size_t)jy1c * wp + jx0c] + wx1 * P[(size_t)jy1c * wp + jx1c]);
    up /= (wys * wxs);

    const float* Eb = Ebuf + (size_t)b * HW;
    float e = Eb[(size_t)oy * Ws + ox];
    float gx = (ox > 0) ? fabsf(e - Eb[(size_t)oy * Ws + ox - 1]) : 0.f;
    float gy = (oy > 0) ? fabsf(e - Eb[(size_t)(oy - 1) * Ws + ox]) : 0.f;
    float g = fminf(fmaxf(0.5f * (gx + gy), 0.f), 1.f);
    float w = 0.7f * fminf(fmaxf(1.f - g * 10.f, 0.f), 1.f);
    float Pv = fminf(fmaxf(e * 10.f, 0.f), 10.f);
    D0[gid] = w * up + (1.f - w) * Pv;
}

// ---------------- zero halos ----------------
__global__ void halo0_k(short* __restrict__ A, short* __restrict__ B2, int Hs, int Ws) {
    int pw = Ws + 2;
    int ne = 2 * pw + 2 * Hs;
    int total = 4 * ne;
    int gid = blockIdx.x * 256 + threadIdx.x;
    if (gid >= total) return;
    int e = gid % ne;
    int t = gid / ne;
    int b = t & 1;
    int buf = t >> 1;
    int yp, xp;
    if (e < pw)            { yp = 0;      xp = e; }
    else if (e < 2 * pw)   { yp = Hs + 1; xp = e - pw; }
    else { int e2 = e - 2 * pw; yp = 1 + (e2 >> 1); xp = (e2 & 1) ? (Ws + 1) : 0; }
    short* p = (buf ? B2 : A) + (((size_t)b * (Hs + 6) + 2 + yp) * pw + xp) * 64;
    short8v z = {0, 0, 0, 0, 0, 0, 0, 0};
#pragma unroll
    for (int j = 0; j < 8; j++) *(short8v*)(p + j * 8) = z;
}

// bijective XCD-chunked swizzle (m204)
__device__ __forceinline__ int xcd_swz(int orig, int nwg) {
    int q = nwg >> 3, r = nwg & 7;
    int xcd = orig & 7, idx = orig >> 3;
    return (xcd < r ? xcd * (q + 1) : r * (q + 1) + (xcd - r) * q) + idx;
}

// ---------------- conv0: 6->64 MFMA implicit GEMM fp16, multi-scale ----------------
__global__ __launch_bounds__(256, 3) void conv0mm_k(
        const short* __restrict__ Xp, const short* __restrict__ WB,
        const float* __restrict__ bias, short* __restrict__ Y, MSD d) {
    const int lane = threadIdx.x & 63;
    const int wv = threadIdx.x >> 6;
    const int b = blockIdx.y;
    const int l15 = lane & 15;
    const int g = lane >> 4;
    int wg = xcd_swz(blockIdx.x, gridDim.x);
    int k = (wg >= d.s0[1]) + (wg >= d.s0[2]);
    int local = wg - d.s0[k];
    const int Hs = d.hs[k], Ws = d.ws[k], pw = Ws + 2, tX = d.tx0[k];
    int ty = local / tX, txi = local - ty * tX;
    const int y = ty * 4 + wv;
    const int x0 = txi * 64;

    const size_t bbase8 = d.xp8[k] + ((size_t)b * (Hs + 6) + 2) * pw * 8;
    const short* Xb = Xp + bbase8;

    f32x4 acc[4][4];
#pragma unroll
    for (int n = 0; n < 4; n++) {
        f32x4 bv;
#pragma unroll
        for (int j = 0; j < 4; j++) bv[j] = bias[16 * n + g * 4 + j];
#pragma unroll
        for (int cg = 0; cg < 4; cg++) acc[n][cg] = bv;
    }

    int vb[4];
#pragma unroll
    for (int cg = 0; cg < 4; cg++)
        vb[cg] = ((y + 1) * pw + (x0 + cg * 16 + l15 + 1)) * 8;

#pragma unroll
    for (int j = 0; j < 3; j++) {
        int tap = 4 * j + g;
        if (tap > 8) tap = 8;
        int toff = ((tap / 3 - 1) * pw + (tap % 3 - 1)) * 8;
        half8v bx[4];
#pragma unroll
        for (int cg = 0; cg < 4; cg++)
            bx[cg] = *(const half8v*)(Xb + vb[cg] + toff);
        const short* wp = WB + (size_t)j * (4 * 512) + lane * 8;
#pragma unroll
        for (int n = 0; n < 4; n++) {
            half8v av = *(const half8v*)(wp + n * 512);
#pragma unroll
            for (int cg = 0; cg < 4; cg++)
                acc[n][cg] = __builtin_amdgcn_mfma_f32_16x16x32_f16(
                    av, bx[cg], acc[n][cg], 0, 0, 0);
        }
    }

    const size_t bbase = d.x64[k] + ((size_t)b * (Hs + 6) + 2) * pw * 64;
#pragma unroll
    for (int cg = 0; cg < 4; cg++) {
        int x = x0 + cg * 16 + l15;
        if (x >= Ws) continue;
        short* out = Y + bbase + ((size_t)(y + 1) * pw + (x + 1)) * 64 + g * 4;
#pragma unroll
        for (int n = 0; n < 4; n++) {
            ushort4 v;
            v.x = f2h(fmaxf(acc[n][cg][0], 0.f));
            v.y = f2h(fmaxf(acc[n][cg][1], 0.f));
            v.z = f2h(fmaxf(acc[n][cg][2], 0.f));
            v.w = f2h(fmaxf(acc[n][cg][3], 0.f));
            *(ushort4*)(out + 16 * n) = v;
        }
    }
}

// ---------------- MFMA implicit-GEMM 3x3 conv fp16, multi-scale ----------------
// Block = 4 waves x 1 row x 64 px (4 rows x 64 px per block).
// Activation tile (6 rows x 66 px x 64 ch, PCH=76 conflict-free) staged in LDS once;
// weights LDS double-buffered per tap; raw non-draining barriers; setprio on MFMA.
// CG=4 amortizes weight LDS reads over 2x pixels (2.25 KB LDS-read per px).
// EPI 0: relu -> padded Y.  EPI 1: head -> packed cof (A,cen) + aux (z,r); sk by kfix.
template <int NF, int CG, int EPI>
__global__ __launch_bounds__(256, 2) void convmm_k(
        const short* __restrict__ X, const short* __restrict__ WB,
        const float* __restrict__ bias, short* __restrict__ Y,
        unsigned short* __restrict__ cof, unsigned short* __restrict__ aux, MSD d) {
    const int lane = threadIdx.x & 63;
    const int wv = threadIdx.x >> 6;
    const int b = blockIdx.y;
    const int l15 = lane & 15;
    const int g = lane >> 4;
    int wg = xcd_swz(blockIdx.x, gridDim.x);
    int k = (wg >= d.s1[1]) + (wg >= d.s1[2]);
    int local = wg - d.s1[k];
    const int Hs = d.hs[k], Ws = d.ws[k], pw = Ws + 2, tX = d.tx1[k];
    int ty = local / tX, txi = local - ty * tX;
    const int y0r = ty * 4;                 // block's first output row
    const int y = y0r + wv;
    const int x0 = txi * (16 * CG);

    const size_t bbase = d.x64[k] + ((size_t)b * (Hs + 6) + 2) * pw * 64;
    const short* Xb = X + bbase;

    constexpr int TAPSZ = 2 * NF * 512;     // shorts per tap of weights
    constexpr int FPW = (2 * NF) / 4;       // weight frags staged per wave per tap
    constexpr int C = 16 * CG + 2;          // 66 tile cols
    constexpr int TR = 6;                   // tile rows (4 outputs + 2 halo)
    constexpr int PCH = 76;                 // padded channel stride (shorts), conflict-free
    __shared__ __attribute__((aligned(16))) short WL[2][TAPSZ];
    __shared__ __attribute__((aligned(16))) short XS[TR * C * PCH];

    f32x4 acc[NF][CG];
#pragma unroll
    for (int n = 0; n < NF; n++) {
        f32x4 bv;
#pragma unroll
        for (int j = 0; j < 4; j++) bv[j] = bias[16 * n + g * 4 + j];
#pragma unroll
        for (int cg = 0; cg < CG; cg++) acc[n][cg] = bv;
    }

    // ---- cooperative activation tile stage: Xb rows y0r..y0r+5, cols x0..x0+C-1 ----
    {
        const int total = TR * C * 8;         // 16B chunks
        for (int c = threadIdx.x; c < total; c += 256) {
            int part = c & 7;
            int px = c >> 3;
            int row = px / C, col = px - row * C;
            short8v val = *(const short8v*)(Xb +
                ((size_t)(y0r + row) * pw + (x0 + col)) * 64 + part * 8);
            *(short8v*)(&XS[(row * C + col) * PCH + part * 8]) = val;
        }
    }
    // ---- weight tap 0 into WL[0] ----
    {
        const short* src = WB + (size_t)(wv * FPW) * 512 + lane * 8;
        short* dst = &WL[0][(wv * FPW) * 512 + lane * 8];
#pragma unroll
        for (int r = 0; r < FPW; r++)
            *(short8v*)(dst + r * 512) = *(const short8v*)(src + r * 512);
    }
    wave_barrier();

#pragma unroll
    for (int tap = 0; tap < 9; tap++) {
        const int cur = tap & 1;
        const int dy = tap / 3 - 1, dx = tap % 3 - 1;
        // issue-early: next tap's weights to regs (vmcnt stays counted across barrier)
        short8v stg[FPW];
        if (tap < 8) {
            const short* src = WB + (size_t)(tap + 1) * TAPSZ + (wv * FPW) * 512 + lane * 8;
#pragma unroll
            for (int r = 0; r < FPW; r++)
                stg[r] = *(const short8v*)(src + r * 512);
        }
        // B fragments from LDS tile
        const int tr = wv + 1 + dy;
        half8v bx[2 * CG];
#pragma unroll
        for (int ks = 0; ks < 2; ks++)
#pragma unroll
            for (int cg = 0; cg < CG; cg++) {
                int tc = cg * 16 + l15 + 1 + dx;
                bx[ks * CG + cg] = *(const half8v*)(
                    &XS[(tr * C + tc) * PCH + ks * 32 + g * 8]);
            }
        __builtin_amdgcn_s_setprio(1);
#pragma unroll
        for (int ks = 0; ks < 2; ks++) {
            half8v wf[NF];
#pragma unroll
            for (int n = 0; n < NF; n++)
                wf[n] = *(const half8v*)(&WL[cur][(ks * NF + n) * 512 + lane * 8]);
#pragma unroll
            for (int n = 0; n < NF; n++)
#pragma unroll
                for (int cg = 0; cg < CG; cg++)
                    acc[n][cg] = __builtin_amdgcn_mfma_f32_16x16x32_f16(
                        wf[n], bx[ks * CG + cg], acc[n][cg], 0, 0, 0);
        }
        __builtin_amdgcn_s_setprio(0);
        if (tap < 8) {
            short* dst = &WL[cur ^ 1][(wv * FPW) * 512 + lane * 8];
#pragma unroll
            for (int r = 0; r < FPW; r++)
                *(short8v*)(dst + r * 512) = stg[r];
        }
        wave_barrier();
    }

    const int HW = Hs * Ws;
#pragma unroll
    for (int cg = 0; cg < CG; cg++) {
        int x = x0 + cg * 16 + l15;
        bool ok = (x < Ws);
        if (EPI == 0) {
            if (!ok) continue;
            short* out = Y + bbase + ((size_t)(y + 1) * pw + (x + 1)) * 64 + g * 4;
#pragma unroll
            for (int n = 0; n < NF; n++) {
                ushort4 v;
                v.x = f2h(fmaxf(acc[n][cg][0], 0.f));
                v.y = f2h(fmaxf(acc[n][cg][1], 0.f));
                v.z = f2h(fmaxf(acc[n][cg][2], 0.f));
                v.w = f2h(fmaxf(acc[n][cg][3], 0.f));
                *(ushort4*)(out + 16 * n) = v;
            }
        } else {
            float t0 = fabsf(acc[0][cg][0]) + fabsf(acc[0][cg][1]) +
                       fabsf(acc[0][cg][2]) + fabsf(acc[0][cg][3]);
            float s0 = t0 + __shfl_xor(t0, 16, 64);
            float t1 = fabsf(acc[1][cg][0]) + fabsf(acc[1][cg][1]) +
                       fabsf(acc[1][cg][2]) + fabsf(acc[1][cg][3]);
            float s1 = t1 + __shfl_xor(t1, 16, 64);
            float inv0 = 1.f / (s0 + 1e-6f);
            float inv1 = 1.f / (s1 + 1e-6f);
            float a0[4], a1[4];
#pragma unroll
            for (int j = 0; j < 4; j++) { a0[j] = acc[0][cg][j] * inv0; a1[j] = acc[1][cg][j] * inv1; }
            float p0 = a0[0] + a0[1] + a0[2] + a0[3];
            float c0 = p0 + __shfl_xor(p0, 16, 64);
            float p1 = a1[0] + a1[1] + a1[2] + a1[3];
            float c1 = p1 + __shfl_xor(p1, 16, 64);

            int pix = y * Ws + x;
            if (ok) {
                size_t pbase = d.pxo[k] + (size_t)b * HW + pix;
                unsigned short* cp = cof + pbase * 32;
                ushort4 va;
                va.x = f2h(a0[0]); va.y = f2h(a0[1]); va.z = f2h(a0[2]); va.w = f2h(a0[3]);
                *(ushort4*)(cp + g * 4) = va;
                if (g < 2) {
                    ushort4 vb2;
                    vb2.x = f2h(a1[0]); vb2.y = f2h(a1[1]); vb2.z = f2h(a1[2]); vb2.w = f2h(a1[3]);
                    *(ushort4*)(cp + 16 + g * 4) = vb2;
                }
                if (g == 0) {
                    cp[24] = f2h(1.f - c0);
                    cp[26] = f2h(1.f - c1);
                }
                if (g == 2) {
                    cp[25] = f2h(1.f - c0);
                    float e0 = acc[1][cg][0], e1 = acc[1][cg][1], e2 = acc[1][cg][2];
                    float m = fmaxf(e0, fmaxf(e1, e2));
                    float q0 = expf(e0 - m), q1 = expf(e1 - m), q2 = expf(e2 - m);
                    float qs = 1.f / (q0 + q1 + q2);
                    unsigned short* ap = aux + pbase * 8;
                    ap[3] = f2h(q0 * qs);
                    ap[4] = f2h(q1 * qs);
                    ap[5] = f2h(q2 * qs);
                }
                if (g == 3) {
                    unsigned short* ap = aux + pbase * 8;
                    ap[0] = f2h(acc[1][cg][0]);
                    ap[1] = f2h(acc[1][cg][1]);
                    ap[2] = f2h(acc[1][cg][2]);
                }
            }
        }
    }
}

// ---------------- kappa fixup: sk = r*(0.1+0.9*sigmoid(z + wcD . D-taps)); fold dlm -> cof ----------------
__global__ __launch_bounds__(256) void kfix_k(const unsigned short* __restrict__ aux,
        unsigned short* __restrict__ cof, const float* __restrict__ D,
        const float* __restrict__ wc, const float* __restrict__ dlm, int Hs, int Ws) {
    int gid = blockIdx.x * 256 + threadIdx.x;
    int HW = Hs * Ws;
    if (gid >= BN * HW) return;
    int b = gid / HW;
    int p = gid - b * HW;
    int y = p / Ws;
    int x = p - y * Ws;
    const unsigned short* ap = aux + ((size_t)b * HW + p) * 8;
    float z0 = h2f(ap[0]), z1 = h2f(ap[1]), z2 = h2f(ap[2]);
    float r0 = h2f(ap[3]), r1 = h2f(ap[4]), r2 = h2f(ap[5]);
    float dsum[3] = {0.f, 0.f, 0.f};
#pragma unroll
    for (int t = 0; t < 9; t++) {
        int yy = y + t / 3 - 1;
        int xx = x + t % 3 - 1;
        if ((unsigned)yy < (unsigned)Hs && (unsigned)xx < (unsigned)Ws) {
            float dv = D[(size_t)b * HW + (size_t)yy * Ws + xx] * 0.1f;
#pragma unroll
            for (int j = 0; j < 3; j++)
                dsum[j] = fmaf(wc[(size_t)(j * 65 + 64) * 9 + t], dv, dsum[j]);
        }
    }
    unsigned short* cp = cof + ((size_t)b * HW + p) * 32;
    float zz[3] = {z0, z1, z2};
    float rr[3] = {r0, r1, r2};
#pragma unroll
    for (int j = 0; j < 3; j++) {
        float kp = 0.1f + 0.9f / (1.f + expf(-(zz[j] + dsum[j])));
        cp[27 + j] = f2h(rr[j] * kp);
    }
    float v = dlm[(size_t)b * HW + p];
    cp[30] = f2h(v >= 0.f ? v : 0.f);
    cp[31] = f2h(v >= 0.f ? 1.f : 0.f);
}

// ---------------- one CSPN propagation step (fully packed coefficients) ----------------
__global__ __launch_bounds__(256) void prop_k(const float* __restrict__ D,
        const unsigned short* __restrict__ cof, float* __restrict__ Dn, int Hs, int Ws) {
    int gid = blockIdx.x * 256 + threadIdx.x;
    int HW = Hs * Ws;
    if (gid >= BN * HW) return;
    int b = gid / HW;
    int p = gid - b * HW;
    int y = p / Ws;
    int x = p - y * Ws;
    const float* Db = D + (size_t)b * HW;
    float Dc = Db[p];

    const unsigned short* cp = cof + ((size_t)b * HW + p) * 32;
    ushort8v q0 = *(const ushort8v*)(cp);
    ushort8v q1 = *(const ushort8v*)(cp + 8);
    ushort8v q2 = *(const ushort8v*)(cp + 16);
    ushort8v q3 = *(const ushort8v*)(cp + 24);

    const int dy_[8] = {-1, -1, -1, 0, 0, 1, 1, 1};
    const int dx_[8] = {-1, 0, 1, -1, 1, -1, 0, 1};
    float mix = Dc;
#pragma unroll
    for (int k = 0; k < 3; k++) {
        int d = 1 << k;
        ushort8v qa = (k == 0) ? q0 : (k == 1) ? q1 : q2;
        float s = h2f(q3[k]) * Dc;
#pragma unroll
        for (int j = 0; j < 8; j++) {
            int yy = y + dy_[j] * d;
            int xx = x + dx_[j] * d;
            float nb = ((unsigned)yy < (unsigned)Hs && (unsigned)xx < (unsigned)Ws)
                           ? Db[(size_t)yy * Ws + xx] : 0.f;
            s = fmaf(h2f(qa[j]), nb, s);
        }
        mix += h2f(q3[3 + k]) * (s - Dc);
    }
    float dl = h2f(q3[6]);
    float ml = h2f(q3[7]);
    Dn[(size_t)b * HW + p] = ml * (0.9f * dl + 0.1f * mix) + (1.f - ml) * mix;
}

extern "C" void kernel_launch(void* const* d_in, const int* in_sizes, int n_in,
                              void* d_out, int out_size, void* d_ws, size_t ws_size,
                              hipStream_t stream) {
    const float* I  = (const float*)d_in[0];
    const float* DL = (const float*)d_in[1];
    const float* ML = (const float*)d_in[2];
    const float* E  = (const float*)d_in[3];
    const float* w0 = (const float*)d_in[4];  const float* b0 = (const float*)d_in[5];
    const float* w1 = (const float*)d_in[6];  const float* b1 = (const float*)d_in[7];
    const float* w2 = (const float*)d_in[8];  const float* b2 = (const float*)d_in[9];
    const float* wa = (const float*)d_in[10]; const float* ba = (const float*)d_in[11];
    const float* wg = (const float*)d_in[12]; const float* bg = (const float*)d_in[13];
    const float* wc = (const float*)d_in[14]; const float* bc = (const float*)d_in[15];

    // scale geometry (index order = processing order: s=4, s=2, s=1)
    const int hsA[3] = {120, 240, 480};
    const int wsA[3] = {160, 320, 640};
    size_t padOff[4] = {0}, xpOff[4] = {0}, pxOff[4] = {0};
    for (int k = 0; k < 3; k++) {
        size_t rows = hsA[k] + 6, cols = wsA[k] + 2;
        padOff[k + 1] = padOff[k] + (size_t)2 * rows * cols * 64;
        xpOff[k + 1]  = xpOff[k]  + (size_t)2 * rows * cols * 8;
        pxOff[k + 1]  = pxOff[k]  + (size_t)2 * hsA[k] * wsA[k];
    }

    size_t off = 0;
    auto carve = [&](size_t bytes) -> void* {
        void* pp = (char*)d_ws + off;
        off = (off + bytes + 255) & ~(size_t)255;
        return pp;
    };
    short* xpad  = (short*)carve(xpOff[3] * 2);
    float* dlm   = (float*)carve(pxOff[3] * 4);
    float* Ebuf  = (float*)carve(pxOff[3] * 4);
    float* D0    = (float*)carve((size_t)BN * HW1 * 4);
    float* D1    = (float*)carve((size_t)BN * HW1 * 4);
    float* Dprev = (float*)carve((size_t)BN * HW1 * 4);
    short* padA  = (short*)carve(padOff[3] * 2 + 65536);
    short* padB  = (short*)carve(padOff[3] * 2 + 65536);
    // aux (pxOff[3]*8 shorts) and cof (pxOff[3]*32 shorts) overlay padB (dead after conv2).
    unsigned short* aux = (unsigned short*)padB;
    unsigned short* cof = (unsigned short*)padB + pxOff[3] * 8;
    short* WB1  = (short*)carve((size_t)18 * 4 * 512 * 2);
    short* WB2  = (short*)carve((size_t)18 * 4 * 512 * 2);
    short* WBh  = (short*)carve((size_t)18 * 2 * 512 * 2);
    short* WB0  = (short*)carve((size_t)3 * 4 * 512 * 2);
    float* hb   = (float*)carve(32 * 4);
    if (off > ws_size) return;

    MSD d;
    d.s0[0] = d.s1[0] = 0;
    for (int k = 0; k < 3; k++) {
        d.hs[k] = hsA[k]; d.ws[k] = wsA[k];
        d.tx0[k] = (wsA[k] + 63) / 64;
        d.tx1[k] = (wsA[k] + 63) / 64;
        d.s0[k + 1] = d.s0[k] + d.tx0[k] * (hsA[k] / 4);
        d.s1[k + 1] = d.s1[k] + d.tx1[k] * (hsA[k] / 4);
        d.xp8[k] = xpOff[k];
        d.x64[k] = padOff[k];
        d.pxo[k] = pxOff[k];
    }

    wtr2_k<<<(18 * 4 * 512 + 255) / 256, 256, 0, stream>>>(w1, WB1);
    wtr2_k<<<(18 * 4 * 512 + 255) / 256, 256, 0, stream>>>(w2, WB2);
    whb_k<<<(18 * 2 * 512 + 255) / 256, 256, 0, stream>>>(wa, wg, wc, WBh);
    wtr0_k<<<(3 * 4 * 512 + 255) / 256, 256, 0, stream>>>(w0, WB0);
    hbias_k<<<1, 32, 0, stream>>>(ba, bg, bc, hb);

    // prep + halo for all scales (independent of D)
    for (int k = 0; k < 3; k++) {
        int Hs = hsA[k], Ws = wsA[k], pw = Ws + 2;
        int nprep = (BN * (Hs + 2) * pw + 255) / 256;
        short* xpk = xpad + xpOff[k];
        float* ebk = Ebuf + pxOff[k];
        float* dlk = dlm + pxOff[k];
        if (k == 0)      prep_k<4><<<nprep, 256, 0, stream>>>(I, DL, ML, E, xpk, ebk, dlk, Hs, Ws);
        else if (k == 1) prep_k<2><<<nprep, 256, 0, stream>>>(I, DL, ML, E, xpk, ebk, dlk, Hs, Ws);
        else             prep_k<1><<<nprep, 256, 0, stream>>>(I, DL, ML, E, xpk, ebk, dlk, Hs, Ws);
        int nhalo = (4 * (2 * pw + 2 * Hs) + 255) / 256;
        halo0_k<<<nhalo, 256, 0, stream>>>(padA + padOff[k], padB + padOff[k], Hs, Ws);
    }

    // merged multi-scale conv pipeline (4 dispatches total)
    conv0mm_k<<<dim3(d.s0[3], BN), 256, 0, stream>>>(xpad, WB0, b0, padA, d);
    convmm_k<4, 4, 0><<<dim3(d.s1[3], BN), 256, 0, stream>>>(padA, WB1, b1, padB,
        nullptr, nullptr, d);
    convmm_k<4, 4, 0><<<dim3(d.s1[3], BN), 256, 0, stream>>>(padB, WB2, b2, padA,
        nullptr, nullptr, d);
    convmm_k<2, 4, 1><<<dim3(d.s1[3], BN), 256, 0, stream>>>(padA, WBh, hb, nullptr,
        cof, aux, d);

    // per-scale: D init -> kappa fixup (also folds anchor into cof) -> 6 prop steps
    for (int si = 0; si < 3; si++) {
        int Hs = hsA[si], Ws = wsA[si], HW = Hs * Ws;
        int nbp = (BN * HW + 255) / 256;
        float* ebk = Ebuf + pxOff[si];
        float* dlk = dlm + pxOff[si];
        unsigned short* cofk = cof + pxOff[si] * 32;
        unsigned short* auxk = aux + pxOff[si] * 8;

        if (si == 0)
            dinit_first_k<<<nbp, 256, 0, stream>>>(ebk, D0, Hs, Ws);
        else
            dinit_blend_k<<<nbp, 256, 0, stream>>>(Dprev, ebk, D0, Hs, Ws);

        kfix_k<<<nbp, 256, 0, stream>>>(auxk, cofk, D0, wc, dlk, Hs, Ws);

        float* Dc = D0;
        float* Dn = D1;
        float* fin = (si < 2) ? Dprev : (float*)d_out;
        for (int t = 0; t < 6; t++) {
            float* tgt = (t == 5) ? fin : Dn;
            prop_k<<<nbp, 256, 0, stream>>>(Dc, cofk, tgt, Hs, Ws);
            if (t < 5) { float* tmp = Dc; Dc = Dn; Dn = tmp; }
        }
    }
}

// Round 23
// 492.441 us; speedup vs baseline: 1.0679x; 1.0679x over previous
//
#include <hip/hip_runtime.h>
#include <hip/hip_bf16.h>

typedef __attribute__((ext_vector_type(8))) short short8v;
typedef __attribute__((ext_vector_type(8))) unsigned short ushort8v;
typedef __attribute__((ext_vector_type(8))) _Float16 half8v;
typedef __attribute__((ext_vector_type(4))) float f32x4;

static constexpr int BN = 2;
static constexpr int H0 = 480, W0 = 640;
static constexpr int HW1 = H0 * W0;

struct MSD {
    int s0[4], s1[4];                 // block-range starts (conv0 / convmm grids), [3]=total
    int hs[3], ws[3];
    int tx0[3], tx1[3];
    unsigned long long xp8[3];        // xpad region offsets (shorts)
    unsigned long long x64[3];        // pad region offsets (shorts)
    unsigned long long pxo[3];        // pixel offsets (px, both batches)
};

__device__ __forceinline__ unsigned short f2h(float f) {
    _Float16 h = (_Float16)f;
    unsigned short s; __builtin_memcpy(&s, &h, 2); return s;
}
__device__ __forceinline__ float h2f(unsigned short s) {
    _Float16 h; __builtin_memcpy(&h, &s, 2); return (float)h;
}

// raw barrier: lgkmcnt(0) for cross-wave LDS visibility; vmcnt stays counted
__device__ __forceinline__ void wave_barrier() {
    asm volatile("s_waitcnt lgkmcnt(0)" ::: "memory");
    __builtin_amdgcn_sched_barrier(0);
    __builtin_amdgcn_s_barrier();
}

// ---------------- MFMA weight transform (64->64) fp16 ----------------
__global__ void wtr2_k(const float* __restrict__ w, short* __restrict__ WB) {
    int gid = blockIdx.x * 256 + threadIdx.x;
    if (gid >= 18 * 4 * 512) return;
    int ie = gid & 7;
    int l  = (gid >> 3) & 63;
    int n  = (gid >> 9) & 3;
    int t2 = gid >> 11;            // 0..17
    int tap = t2 >> 1, ks = t2 & 1;
    int o = 16 * n + (l & 15);
    int c = 32 * ks + (l >> 4) * 8 + ie;
    WB[gid] = (short)f2h(w[(size_t)(o * 64 + c) * 9 + tap]);
}

// ---------------- conv0 MFMA weight transform fp16 ----------------
__global__ void wtr0_k(const float* __restrict__ w, short* __restrict__ WB) {
    int gid = blockIdx.x * 256 + threadIdx.x;
    if (gid >= 3 * 4 * 512) return;
    int ie = gid & 7;
    int l  = (gid >> 3) & 63;
    int n  = (gid >> 9) & 3;
    int j  = gid >> 11;            // 0..2
    int o = 16 * n + (l & 15);
    int g = l >> 4;
    int tap = 4 * j + g;
    float wv = (tap < 9 && ie < 6) ? w[(size_t)(o * 6 + ie) * 9 + tap] : 0.f;
    WB[gid] = (short)f2h(wv);
}

// ---------------- head weight transform fp16 ----------------
__global__ void whb_k(const float* __restrict__ wa, const float* __restrict__ wg,
                      const float* __restrict__ wc, short* __restrict__ WB) {
    int gid = blockIdx.x * 256 + threadIdx.x;
    if (gid >= 18 * 2 * 512) return;
    int ie = gid & 7;
    int l  = (gid >> 3) & 63;
    int n  = (gid >> 9) & 1;
    int t2 = gid >> 10;            // 0..17
    int tap = t2 >> 1, ks = t2 & 1;
    int o = 16 * n + (l & 15);
    int c = 32 * ks + (l >> 4) * 8 + ie;
    float wv = 0.f;
    if (o < 24)                 wv = wa[(size_t)(o * 64 + c) * 9 + tap];
    else if (o >= 24 && o < 27) wv = wg[(size_t)((o - 24) * 64 + c) * 9 + tap];
    else if (o >= 28 && o < 31) wv = wc[(size_t)((o - 28) * 65 + c) * 9 + tap];
    WB[gid] = (short)f2h(wv);
}

__global__ void hbias_k(const float* __restrict__ ba, const float* __restrict__ bg,
                        const float* __restrict__ bc, float* __restrict__ hb) {
    int o = threadIdx.x;
    if (o >= 32) return;
    float v = 0.f;
    if (o < 24) v = ba[o];
    else if (o < 27) v = bg[o - 24];
    else if (o >= 28 && o < 31) v = bc[o - 28];
    hb[o] = v;
}

// ---------------- fused per-scale prep ----------------
template <int F>
__global__ void prep_k(const float* __restrict__ I, const float* __restrict__ DL,
                       const float* __restrict__ ML, const float* __restrict__ E,
                       short* __restrict__ Xp, float* __restrict__ Ebuf,
                       float* __restrict__ dlm, int Hs, int Ws) {
    const int pw = Ws + 2;
    int gid = blockIdx.x * 256 + threadIdx.x;
    int total = BN * (Hs + 2) * pw;
    if (gid >= total) return;
    int xp = gid % pw;
    int yp = (gid / pw) % (Hs + 2);
    int b = gid / (pw * (Hs + 2));
    short8v v = {0, 0, 0, 0, 0, 0, 0, 0};
    if (yp >= 1 && yp <= Hs && xp >= 1 && xp <= Ws) {
        int oy = yp - 1, ox = xp - 1;
        if constexpr (F == 1) {
            int p = oy * W0 + ox;
#pragma unroll
            for (int c = 0; c < 3; c++)
                v[c] = (short)f2h(I[(size_t)(b * 3 + c) * HW1 + p]);
            float e = fminf(fmaxf(E[(size_t)b * HW1 + p], 0.f), 1.f);
            v[5] = (short)f2h(e);
            Ebuf[(size_t)b * Hs * Ws + p] = e;
            float m = ML[(size_t)b * HW1 + p] > 0.f ? 1.f : 0.f;
            float s = DL[(size_t)b * HW1 + p] * m;
            float dls = m > 0.f ? s / (m + 1e-6f) : 0.f;
            v[3] = (short)f2h(dls);
            v[4] = (short)f2h(m);
            dlm[(size_t)b * Hs * Ws + p] = m > 0.f ? dls : -1.f;
        } else {
            constexpr int NT = 2 * F;
            float wy[NT], wx[NT];
            float sy = (oy + 0.5f) * F - 0.5f;
            int jly = F * oy - (F + 1) / 2;
            float wys = 0.f;
#pragma unroll
            for (int t = 0; t < NT; t++) {
                int j = jly + t;
                float w = fmaxf(1.f - fabsf(sy - (float)j) / (float)F, 0.f);
                if (j < 0 || j >= H0) w = 0.f;
                wy[t] = w; wys += w;
            }
            float sx = (ox + 0.5f) * F - 0.5f;
            int jlx = F * ox - (F + 1) / 2;
            float wxs = 0.f;
#pragma unroll
            for (int t = 0; t < NT; t++) {
                int j = jlx + t;
                float w = fmaxf(1.f - fabsf(sx - (float)j) / (float)F, 0.f);
                if (j < 0 || j >= W0) w = 0.f;
                wx[t] = w; wxs += w;
            }
            float inv = 1.f / (wys * wxs);
#pragma unroll
            for (int c = 0; c < 3; c++) {
                const float* ip = I + (size_t)(b * 3 + c) * HW1;
                float acc = 0.f;
#pragma unroll
                for (int ty = 0; ty < NT; ty++) {
                    if (wy[ty] == 0.f) continue;
                    const float* row = ip + (size_t)(jly + ty) * W0;
                    float r = 0.f;
#pragma unroll
                    for (int tx = 0; tx < NT; tx++)
                        if (wx[tx] != 0.f) r += wx[tx] * row[jlx + tx];
                    acc += wy[ty] * r;
                }
                v[c] = (short)f2h(acc * inv);
            }
            {
                const float* ip = E + (size_t)b * HW1;
                float acc = 0.f;
#pragma unroll
                for (int ty = 0; ty < NT; ty++) {
                    if (wy[ty] == 0.f) continue;
                    const float* row = ip + (size_t)(jly + ty) * W0;
                    float r = 0.f;
#pragma unroll
                    for (int tx = 0; tx < NT; tx++)
                        if (wx[tx] != 0.f) r += wx[tx] * row[jlx + tx];
                    acc += wy[ty] * r;
                }
                acc = fminf(fmaxf(acc * inv, 0.f), 1.f);
                v[5] = (short)f2h(acc);
                Ebuf[(size_t)b * Hs * Ws + oy * Ws + ox] = acc;
            }
            {
                float s = 0.f, c = 0.f;
#pragma unroll
                for (int dy = 0; dy < F; dy++)
#pragma unroll
                    for (int dx = 0; dx < F; dx++) {
                        size_t idx = ((size_t)b * H0 + (oy * F + dy)) * W0 + (ox * F + dx);
                        float m = ML[idx] > 0.f ? 1.f : 0.f;
                        s += DL[idx] * m;
                        c += m;
                    }
                float dls = c > 0.f ? s / (c + 1e-6f) : 0.f;
                v[3] = (short)f2h(dls);
                v[4] = (short)f2h(c > 0.f ? 1.f : 0.f);
                dlm[(size_t)b * Hs * Ws + oy * Ws + ox] = c > 0.f ? dls : -1.f;
            }
        }
    }
    *(short8v*)(Xp + (((size_t)b * (Hs + 6) + 2 + yp) * pw + xp) * 8) = v;
}

// ---------------- D init, first scale ----------------
__global__ void dinit_first_k(const float* __restrict__ Ebuf, float* __restrict__ D0,
                              int Hs, int Ws) {
    int gid = blockIdx.x * 256 + threadIdx.x;
    int HW = Hs * Ws;
    if (gid >= BN * HW) return;
    float e = Ebuf[gid];
    D0[gid] = fminf(fmaxf(e * 10.f, 0.f), 10.f);
}

// ---------------- D init, later scales ----------------
__global__ void dinit_blend_k(const float* __restrict__ Dp, const float* __restrict__ Ebuf,
                              float* __restrict__ D0, int Hs, int Ws) {
    int gid = blockIdx.x * 256 + threadIdx.x;
    int HW = Hs * Ws;
    if (gid >= BN * HW) return;
    int ox = gid % Ws;
    int oy = (gid / Ws) % Hs;
    int b = gid / HW;
    int hp = Hs / 2, wp = Ws / 2;
    const float* P = Dp + (size_t)b * hp * wp;

    float ty = 0.5f * oy - 0.25f;
    int jy = (int)floorf(ty);
    float fy = ty - jy;
    float wy0 = 1.f - fy, wy1 = fy;
    bool v0 = (jy >= 0) && (jy < hp);
    bool v1 = (jy + 1 >= 0) && (jy + 1 < hp);
    if (!v0) wy0 = 0.f;
    if (!v1) wy1 = 0.f;
    float wys = wy0 + wy1;

    float tx = 0.5f * ox - 0.25f;
    int jx = (int)floorf(tx);
    float fx = tx - jx;
    float wx0 = 1.f - fx, wx1 = fx;
    bool u0 = (jx >= 0) && (jx < wp);
    bool u1 = (jx + 1 >= 0) && (jx + 1 < wp);
    if (!u0) wx0 = 0.f;
    if (!u1) wx1 = 0.f;
    float wxs = wx0 + wx1;

    int jy0c = v0 ? jy : 0, jy1c = v1 ? (jy + 1) : 0;
    int jx0c = u0 ? jx : 0, jx1c = u1 ? (jx + 1) : 0;
    float up = wy0 * (wx0 * P[(size_t)jy0c * wp + jx0c] + wx1 * P[(size_t)jy0c * wp + jx1c])
             + wy1 * (wx0 * P[(size_t)jy1c * wp + jx0c] + wx1 * P[(size_t)jy1c * wp + jx1c]);
    up /= (wys * wxs);

    const float* Eb = Ebuf + (size_t)b * HW;
    float e = Eb[(size_t)oy * Ws + ox];
    float gx = (ox > 0) ? fabsf(e - Eb[(size_t)oy * Ws + ox - 1]) : 0.f;
    float gy = (oy > 0) ? fabsf(e - Eb[(size_t)(oy - 1) * Ws + ox]) : 0.f;
    float g = fminf(fmaxf(0.5f * (gx + gy), 0.f), 1.f);
    float w = 0.7f * fminf(fmaxf(1.f - g * 10.f, 0.f), 1.f);
    float Pv = fminf(fmaxf(e * 10.f, 0.f), 10.f);
    D0[gid] = w * up + (1.f - w) * Pv;
}

// ---------------- zero halos ----------------
__global__ void halo0_k(short* __restrict__ A, short* __restrict__ B2, int Hs, int Ws) {
    int pw = Ws + 2;
    int ne = 2 * pw + 2 * Hs;
    int total = 4 * ne;
    int gid = blockIdx.x * 256 + threadIdx.x;
    if (gid >= total) return;
    int e = gid % ne;
    int t = gid / ne;
    int b = t & 1;
    int buf = t >> 1;
    int yp, xp;
    if (e < pw)            { yp = 0;      xp = e; }
    else if (e < 2 * pw)   { yp = Hs + 1; xp = e - pw; }
    else { int e2 = e - 2 * pw; yp = 1 + (e2 >> 1); xp = (e2 & 1) ? (Ws + 1) : 0; }
    short* p = (buf ? B2 : A) + (((size_t)b * (Hs + 6) + 2 + yp) * pw + xp) * 64;
    short8v z = {0, 0, 0, 0, 0, 0, 0, 0};
#pragma unroll
    for (int j = 0; j < 8; j++) *(short8v*)(p + j * 8) = z;
}

// bijective XCD-chunked swizzle (m204)
__device__ __forceinline__ int xcd_swz(int orig, int nwg) {
    int q = nwg >> 3, r = nwg & 7;
    int xcd = orig & 7, idx = orig >> 3;
    return (xcd < r ? xcd * (q + 1) : r * (q + 1) + (xcd - r) * q) + idx;
}

// ---------------- conv0: 6->64 MFMA implicit GEMM fp16, multi-scale ----------------
__global__ __launch_bounds__(256, 3) void conv0mm_k(
        const short* __restrict__ Xp, const short* __restrict__ WB,
        const float* __restrict__ bias, short* __restrict__ Y, MSD d) {
    const int lane = threadIdx.x & 63;
    const int wv = threadIdx.x >> 6;
    const int b = blockIdx.y;
    const int l15 = lane & 15;
    const int g = lane >> 4;
    int wg = xcd_swz(blockIdx.x, gridDim.x);
    int k = (wg >= d.s0[1]) + (wg >= d.s0[2]);
    int local = wg - d.s0[k];
    const int Hs = d.hs[k], Ws = d.ws[k], pw = Ws + 2, tX = d.tx0[k];
    int ty = local / tX, txi = local - ty * tX;
    const int y = ty * 4 + wv;
    const int x0 = txi * 64;

    const size_t bbase8 = d.xp8[k] + ((size_t)b * (Hs + 6) + 2) * pw * 8;
    const short* Xb = Xp + bbase8;

    f32x4 acc[4][4];
#pragma unroll
    for (int n = 0; n < 4; n++) {
        f32x4 bv;
#pragma unroll
        for (int j = 0; j < 4; j++) bv[j] = bias[16 * n + g * 4 + j];
#pragma unroll
        for (int cg = 0; cg < 4; cg++) acc[n][cg] = bv;
    }

    int vb[4];
#pragma unroll
    for (int cg = 0; cg < 4; cg++)
        vb[cg] = ((y + 1) * pw + (x0 + cg * 16 + l15 + 1)) * 8;

#pragma unroll
    for (int j = 0; j < 3; j++) {
        int tap = 4 * j + g;
        if (tap > 8) tap = 8;
        int toff = ((tap / 3 - 1) * pw + (tap % 3 - 1)) * 8;
        half8v bx[4];
#pragma unroll
        for (int cg = 0; cg < 4; cg++)
            bx[cg] = *(const half8v*)(Xb + vb[cg] + toff);
        const short* wp = WB + (size_t)j * (4 * 512) + lane * 8;
#pragma unroll
        for (int n = 0; n < 4; n++) {
            half8v av = *(const half8v*)(wp + n * 512);
#pragma unroll
            for (int cg = 0; cg < 4; cg++)
                acc[n][cg] = __builtin_amdgcn_mfma_f32_16x16x32_f16(
                    av, bx[cg], acc[n][cg], 0, 0, 0);
        }
    }

    const size_t bbase = d.x64[k] + ((size_t)b * (Hs + 6) + 2) * pw * 64;
#pragma unroll
    for (int cg = 0; cg < 4; cg++) {
        int x = x0 + cg * 16 + l15;
        if (x >= Ws) continue;
        short* out = Y + bbase + ((size_t)(y + 1) * pw + (x + 1)) * 64 + g * 4;
#pragma unroll
        for (int n = 0; n < 4; n++) {
            ushort4 v;
            v.x = f2h(fmaxf(acc[n][cg][0], 0.f));
            v.y = f2h(fmaxf(acc[n][cg][1], 0.f));
            v.z = f2h(fmaxf(acc[n][cg][2], 0.f));
            v.w = f2h(fmaxf(acc[n][cg][3], 0.f));
            *(ushort4*)(out + 16 * n) = v;
        }
    }
}

// ---------------- MFMA implicit-GEMM 3x3 conv fp16, multi-scale, CG col-groups ----------------
// ACTIVATION TILE STAGED IN LDS (6 rows x 34 px x 64 ch, PCH=76 conflict-free pad): one bulk
// global load per block, tap loop reads B via ds_read_b128 (zero in-loop global B traffic).
// Weights LDS double-buffered per tap (issue-early/write-late); raw non-draining barriers.
// EPI 0: relu -> padded Y.  EPI 1: head -> packed cof (A,cen) + aux (z,r); sk by kfix.
template <int NF, int CG, int EPI>
__global__ __launch_bounds__(256, 2) void convmm_k(
        const short* __restrict__ X, const short* __restrict__ WB,
        const float* __restrict__ bias, short* __restrict__ Y,
        unsigned short* __restrict__ cof, unsigned short* __restrict__ aux, MSD d) {
    const int lane = threadIdx.x & 63;
    const int wv = threadIdx.x >> 6;
    const int b = blockIdx.y;
    const int l15 = lane & 15;
    const int g = lane >> 4;
    int wg = xcd_swz(blockIdx.x, gridDim.x);
    int k = (wg >= d.s1[1]) + (wg >= d.s1[2]);
    int local = wg - d.s1[k];
    const int Hs = d.hs[k], Ws = d.ws[k], pw = Ws + 2, tX = d.tx1[k];
    int ty = local / tX, txi = local - ty * tX;
    const int y0r = ty * 4;
    const int y = y0r + wv;
    const int x0 = txi * (16 * CG);

    const size_t bbase = d.x64[k] + ((size_t)b * (Hs + 6) + 2) * pw * 64;
    const short* Xb = X + bbase;

    constexpr int TAPSZ = 2 * NF * 512;     // shorts per tap of weights
    constexpr int FPW = (2 * NF) / 4;       // weight frags staged per wave per tap
    constexpr int C = 16 * CG + 2;          // 34 tile cols
    constexpr int TR = 6;                   // tile rows (4 outputs + 2 halo)
    constexpr int PCH = 76;                 // padded channel stride (shorts), conflict-free
    __shared__ __attribute__((aligned(16))) short WL[2][TAPSZ];
    __shared__ __attribute__((aligned(16))) short XS[TR * C * PCH];

    f32x4 acc[NF][CG];
#pragma unroll
    for (int n = 0; n < NF; n++) {
        f32x4 bv;
#pragma unroll
        for (int j = 0; j < 4; j++) bv[j] = bias[16 * n + g * 4 + j];
#pragma unroll
        for (int cg = 0; cg < CG; cg++) acc[n][cg] = bv;
    }

    // ---- cooperative activation tile stage: Xb rows y0r..y0r+5, cols x0..x0+C-1 ----
    {
        const int total = TR * C * 8;         // 16B chunks
        for (int c = threadIdx.x; c < total; c += 256) {
            int part = c & 7;
            int px = c >> 3;
            int row = px / C, col = px - row * C;
            short8v val = *(const short8v*)(Xb +
                ((size_t)(y0r + row) * pw + (x0 + col)) * 64 + part * 8);
            *(short8v*)(&XS[(row * C + col) * PCH + part * 8]) = val;
        }
    }
    // ---- weight tap 0 into WL[0] ----
    {
        const short* src = WB + (size_t)(wv * FPW) * 512 + lane * 8;
        short* dst = &WL[0][(wv * FPW) * 512 + lane * 8];
#pragma unroll
        for (int r = 0; r < FPW; r++)
            *(short8v*)(dst + r * 512) = *(const short8v*)(src + r * 512);
    }
    wave_barrier();

#pragma unroll
    for (int tap = 0; tap < 9; tap++) {
        const int cur = tap & 1;
        const int dy = tap / 3 - 1, dx = tap % 3 - 1;
        // issue-early: next tap's weights to regs (vmcnt stays counted across barrier)
        short8v stg[FPW];
        if (tap < 8) {
            const short* src = WB + (size_t)(tap + 1) * TAPSZ + (wv * FPW) * 512 + lane * 8;
#pragma unroll
            for (int r = 0; r < FPW; r++)
                stg[r] = *(const short8v*)(src + r * 512);
        }
        // B fragments from LDS tile
        const int tr = wv + 1 + dy;
        half8v bx[2 * CG];
#pragma unroll
        for (int ks = 0; ks < 2; ks++)
#pragma unroll
            for (int cg = 0; cg < CG; cg++) {
                int tc = cg * 16 + l15 + 1 + dx;
                bx[ks * CG + cg] = *(const half8v*)(
                    &XS[(tr * C + tc) * PCH + ks * 32 + g * 8]);
            }
        __builtin_amdgcn_s_setprio(1);
#pragma unroll
        for (int ks = 0; ks < 2; ks++) {
            half8v wf[NF];
#pragma unroll
            for (int n = 0; n < NF; n++)
                wf[n] = *(const half8v*)(&WL[cur][(ks * NF + n) * 512 + lane * 8]);
#pragma unroll
            for (int n = 0; n < NF; n++)
#pragma unroll
                for (int cg = 0; cg < CG; cg++)
                    acc[n][cg] = __builtin_amdgcn_mfma_f32_16x16x32_f16(
                        wf[n], bx[ks * CG + cg], acc[n][cg], 0, 0, 0);
        }
        __builtin_amdgcn_s_setprio(0);
        if (tap < 8) {
            short* dst = &WL[cur ^ 1][(wv * FPW) * 512 + lane * 8];
#pragma unroll
            for (int r = 0; r < FPW; r++)
                *(short8v*)(dst + r * 512) = stg[r];
        }
        wave_barrier();
    }

    const int HW = Hs * Ws;
#pragma unroll
    for (int cg = 0; cg < CG; cg++) {
        int x = x0 + cg * 16 + l15;
        bool ok = (x < Ws);
        if (EPI == 0) {
            if (!ok) continue;
            short* out = Y + bbase + ((size_t)(y + 1) * pw + (x + 1)) * 64 + g * 4;
#pragma unroll
            for (int n = 0; n < NF; n++) {
                ushort4 v;
                v.x = f2h(fmaxf(acc[n][cg][0], 0.f));
                v.y = f2h(fmaxf(acc[n][cg][1], 0.f));
                v.z = f2h(fmaxf(acc[n][cg][2], 0.f));
                v.w = f2h(fmaxf(acc[n][cg][3], 0.f));
                *(ushort4*)(out + 16 * n) = v;
            }
        } else {
            float t0 = fabsf(acc[0][cg][0]) + fabsf(acc[0][cg][1]) +
                       fabsf(acc[0][cg][2]) + fabsf(acc[0][cg][3]);
            float s0 = t0 + __shfl_xor(t0, 16, 64);
            float t1 = fabsf(acc[1][cg][0]) + fabsf(acc[1][cg][1]) +
                       fabsf(acc[1][cg][2]) + fabsf(acc[1][cg][3]);
            float s1 = t1 + __shfl_xor(t1, 16, 64);
            float inv0 = 1.f / (s0 + 1e-6f);
            float inv1 = 1.f / (s1 + 1e-6f);
            float a0[4], a1[4];
#pragma unroll
            for (int j = 0; j < 4; j++) { a0[j] = acc[0][cg][j] * inv0; a1[j] = acc[1][cg][j] * inv1; }
            float p0 = a0[0] + a0[1] + a0[2] + a0[3];
            float c0 = p0 + __shfl_xor(p0, 16, 64);
            float p1 = a1[0] + a1[1] + a1[2] + a1[3];
            float c1 = p1 + __shfl_xor(p1, 16, 64);

            int pix = y * Ws + x;
            if (ok) {
                size_t pbase = d.pxo[k] + (size_t)b * HW + pix;
                unsigned short* cp = cof + pbase * 32;
                ushort4 va;
                va.x = f2h(a0[0]); va.y = f2h(a0[1]); va.z = f2h(a0[2]); va.w = f2h(a0[3]);
                *(ushort4*)(cp + g * 4) = va;
                if (g < 2) {
                    ushort4 vb2;
                    vb2.x = f2h(a1[0]); vb2.y = f2h(a1[1]); vb2.z = f2h(a1[2]); vb2.w = f2h(a1[3]);
                    *(ushort4*)(cp + 16 + g * 4) = vb2;
                }
                if (g == 0) {
                    cp[24] = f2h(1.f - c0);
                    cp[26] = f2h(1.f - c1);
                }
                if (g == 2) {
                    cp[25] = f2h(1.f - c0);
                    float e0 = acc[1][cg][0], e1 = acc[1][cg][1], e2 = acc[1][cg][2];
                    float m = fmaxf(e0, fmaxf(e1, e2));
                    float q0 = expf(e0 - m), q1 = expf(e1 - m), q2 = expf(e2 - m);
                    float qs = 1.f / (q0 + q1 + q2);
                    unsigned short* ap = aux + pbase * 8;
                    ap[3] = f2h(q0 * qs);
                    ap[4] = f2h(q1 * qs);
                    ap[5] = f2h(q2 * qs);
                }
                if (g == 3) {
                    unsigned short* ap = aux + pbase * 8;
                    ap[0] = f2h(acc[1][cg][0]);
                    ap[1] = f2h(acc[1][cg][1]);
                    ap[2] = f2h(acc[1][cg][2]);
                }
            }
        }
    }
}

// ---------------- kappa fixup: sk = r*(0.1+0.9*sigmoid(z + wcD . D-taps)); fold dlm -> cof ----------------
__global__ __launch_bounds__(256) void kfix_k(const unsigned short* __restrict__ aux,
        unsigned short* __restrict__ cof, const float* __restrict__ D,
        const float* __restrict__ wc, const float* __restrict__ dlm, int Hs, int Ws) {
    int gid = blockIdx.x * 256 + threadIdx.x;
    int HW = Hs * Ws;
    if (gid >= BN * HW) return;
    int b = gid / HW;
    int p = gid - b * HW;
    int y = p / Ws;
    int x = p - y * Ws;
    const unsigned short* ap = aux + ((size_t)b * HW + p) * 8;
    float z0 = h2f(ap[0]), z1 = h2f(ap[1]), z2 = h2f(ap[2]);
    float r0 = h2f(ap[3]), r1 = h2f(ap[4]), r2 = h2f(ap[5]);
    float dsum[3] = {0.f, 0.f, 0.f};
#pragma unroll
    for (int t = 0; t < 9; t++) {
        int yy = y + t / 3 - 1;
        int xx = x + t % 3 - 1;
        if ((unsigned)yy < (unsigned)Hs && (unsigned)xx < (unsigned)Ws) {
            float dv = D[(size_t)b * HW + (size_t)yy * Ws + xx] * 0.1f;
#pragma unroll
            for (int j = 0; j < 3; j++)
                dsum[j] = fmaf(wc[(size_t)(j * 65 + 64) * 9 + t], dv, dsum[j]);
        }
    }
    unsigned short* cp = cof + ((size_t)b * HW + p) * 32;
    float zz[3] = {z0, z1, z2};
    float rr[3] = {r0, r1, r2};
#pragma unroll
    for (int j = 0; j < 3; j++) {
        float kp = 0.1f + 0.9f / (1.f + expf(-(zz[j] + dsum[j])));
        cp[27 + j] = f2h(rr[j] * kp);
    }
    float v = dlm[(size_t)b * HW + p];
    cp[30] = f2h(v >= 0.f ? v : 0.f);
    cp[31] = f2h(v >= 0.f ? 1.f : 0.f);
}

// ---------------- one CSPN propagation step (fully packed coefficients) ----------------
__global__ __launch_bounds__(256) void prop_k(const float* __restrict__ D,
        const unsigned short* __restrict__ cof, float* __restrict__ Dn, int Hs, int Ws) {
    int gid = blockIdx.x * 256 + threadIdx.x;
    int HW = Hs * Ws;
    if (gid >= BN * HW) return;
    int b = gid / HW;
    int p = gid - b * HW;
    int y = p / Ws;
    int x = p - y * Ws;
    const float* Db = D + (size_t)b * HW;
    float Dc = Db[p];

    const unsigned short* cp = cof + ((size_t)b * HW + p) * 32;
    ushort8v q0 = *(const ushort8v*)(cp);
    ushort8v q1 = *(const ushort8v*)(cp + 8);
    ushort8v q2 = *(const ushort8v*)(cp + 16);
    ushort8v q3 = *(const ushort8v*)(cp + 24);

    const int dy_[8] = {-1, -1, -1, 0, 0, 1, 1, 1};
    const int dx_[8] = {-1, 0, 1, -1, 1, -1, 0, 1};
    float mix = Dc;
#pragma unroll
    for (int k = 0; k < 3; k++) {
        int d = 1 << k;
        ushort8v qa = (k == 0) ? q0 : (k == 1) ? q1 : q2;
        float s = h2f(q3[k]) * Dc;
#pragma unroll
        for (int j = 0; j < 8; j++) {
            int yy = y + dy_[j] * d;
            int xx = x + dx_[j] * d;
            float nb = ((unsigned)yy < (unsigned)Hs && (unsigned)xx < (unsigned)Ws)
                           ? Db[(size_t)yy * Ws + xx] : 0.f;
            s = fmaf(h2f(qa[j]), nb, s);
        }
        mix += h2f(q3[3 + k]) * (s - Dc);
    }
    float dl = h2f(q3[6]);
    float ml = h2f(q3[7]);
    Dn[(size_t)b * HW + p] = ml * (0.9f * dl + 0.1f * mix) + (1.f - ml) * mix;
}

extern "C" void kernel_launch(void* const* d_in, const int* in_sizes, int n_in,
                              void* d_out, int out_size, void* d_ws, size_t ws_size,
                              hipStream_t stream) {
    const float* I  = (const float*)d_in[0];
    const float* DL = (const float*)d_in[1];
    const float* ML = (const float*)d_in[2];
    const float* E  = (const float*)d_in[3];
    const float* w0 = (const float*)d_in[4];  const float* b0 = (const float*)d_in[5];
    const float* w1 = (const float*)d_in[6];  const float* b1 = (const float*)d_in[7];
    const float* w2 = (const float*)d_in[8];  const float* b2 = (const float*)d_in[9];
    const float* wa = (const float*)d_in[10]; const float* ba = (const float*)d_in[11];
    const float* wg = (const float*)d_in[12]; const float* bg = (const float*)d_in[13];
    const float* wc = (const float*)d_in[14]; const float* bc = (const float*)d_in[15];

    // scale geometry (index order = processing order: s=4, s=2, s=1)
    const int hsA[3] = {120, 240, 480};
    const int wsA[3] = {160, 320, 640};
    size_t padOff[4] = {0}, xpOff[4] = {0}, pxOff[4] = {0};
    for (int k = 0; k < 3; k++) {
        size_t rows = hsA[k] + 6, cols = wsA[k] + 2;
        padOff[k + 1] = padOff[k] + (size_t)2 * rows * cols * 64;
        xpOff[k + 1]  = xpOff[k]  + (size_t)2 * rows * cols * 8;
        pxOff[k + 1]  = pxOff[k]  + (size_t)2 * hsA[k] * wsA[k];
    }

    size_t off = 0;
    auto carve = [&](size_t bytes) -> void* {
        void* pp = (char*)d_ws + off;
        off = (off + bytes + 255) & ~(size_t)255;
        return pp;
    };
    short* xpad  = (short*)carve(xpOff[3] * 2);
    float* dlm   = (float*)carve(pxOff[3] * 4);
    float* Ebuf  = (float*)carve(pxOff[3] * 4);
    float* D0    = (float*)carve((size_t)BN * HW1 * 4);
    float* D1    = (float*)carve((size_t)BN * HW1 * 4);
    float* Dprev = (float*)carve((size_t)BN * HW1 * 4);
    short* padA  = (short*)carve(padOff[3] * 2 + 65536);
    short* padB  = (short*)carve(padOff[3] * 2 + 65536);
    // aux (pxOff[3]*8 shorts) and cof (pxOff[3]*32 shorts) overlay padB (dead after conv2).
    unsigned short* aux = (unsigned short*)padB;
    unsigned short* cof = (unsigned short*)padB + pxOff[3] * 8;
    short* WB1  = (short*)carve((size_t)18 * 4 * 512 * 2);
    short* WB2  = (short*)carve((size_t)18 * 4 * 512 * 2);
    short* WBh  = (short*)carve((size_t)18 * 2 * 512 * 2);
    short* WB0  = (short*)carve((size_t)3 * 4 * 512 * 2);
    float* hb   = (float*)carve(32 * 4);
    if (off > ws_size) return;

    MSD d;
    d.s0[0] = d.s1[0] = 0;
    for (int k = 0; k < 3; k++) {
        d.hs[k] = hsA[k]; d.ws[k] = wsA[k];
        d.tx0[k] = (wsA[k] + 63) / 64;
        d.tx1[k] = (wsA[k] + 31) / 32;
        d.s0[k + 1] = d.s0[k] + d.tx0[k] * (hsA[k] / 4);
        d.s1[k + 1] = d.s1[k] + d.tx1[k] * (hsA[k] / 4);
        d.xp8[k] = xpOff[k];
        d.x64[k] = padOff[k];
        d.pxo[k] = pxOff[k];
    }

    wtr2_k<<<(18 * 4 * 512 + 255) / 256, 256, 0, stream>>>(w1, WB1);
    wtr2_k<<<(18 * 4 * 512 + 255) / 256, 256, 0, stream>>>(w2, WB2);
    whb_k<<<(18 * 2 * 512 + 255) / 256, 256, 0, stream>>>(wa, wg, wc, WBh);
    wtr0_k<<<(3 * 4 * 512 + 255) / 256, 256, 0, stream>>>(w0, WB0);
    hbias_k<<<1, 32, 0, stream>>>(ba, bg, bc, hb);

    // prep + halo for all scales (independent of D)
    for (int k = 0; k < 3; k++) {
        int Hs = hsA[k], Ws = wsA[k], pw = Ws + 2;
        int nprep = (BN * (Hs + 2) * pw + 255) / 256;
        short* xpk = xpad + xpOff[k];
        float* ebk = Ebuf + pxOff[k];
        float* dlk = dlm + pxOff[k];
        if (k == 0)      prep_k<4><<<nprep, 256, 0, stream>>>(I, DL, ML, E, xpk, ebk, dlk, Hs, Ws);
        else if (k == 1) prep_k<2><<<nprep, 256, 0, stream>>>(I, DL, ML, E, xpk, ebk, dlk, Hs, Ws);
        else             prep_k<1><<<nprep, 256, 0, stream>>>(I, DL, ML, E, xpk, ebk, dlk, Hs, Ws);
        int nhalo = (4 * (2 * pw + 2 * Hs) + 255) / 256;
        halo0_k<<<nhalo, 256, 0, stream>>>(padA + padOff[k], padB + padOff[k], Hs, Ws);
    }

    // merged multi-scale conv pipeline (4 dispatches total)
    conv0mm_k<<<dim3(d.s0[3], BN), 256, 0, stream>>>(xpad, WB0, b0, padA, d);
    convmm_k<4, 2, 0><<<dim3(d.s1[3], BN), 256, 0, stream>>>(padA, WB1, b1, padB,
        nullptr, nullptr, d);
    convmm_k<4, 2, 0><<<dim3(d.s1[3], BN), 256, 0, stream>>>(padB, WB2, b2, padA,
        nullptr, nullptr, d);
    convmm_k<2, 2, 1><<<dim3(d.s1[3], BN), 256, 0, stream>>>(padA, WBh, hb, nullptr,
        cof, aux, d);

    // per-scale: D init -> kappa fixup (also folds anchor into cof) -> 6 prop steps
    for (int si = 0; si < 3; si++) {
        int Hs = hsA[si], Ws = wsA[si], HW = Hs * Ws;
        int nbp = (BN * HW + 255) / 256;
        float* ebk = Ebuf + pxOff[si];
        float* dlk = dlm + pxOff[si];
        unsigned short* cofk = cof + pxOff[si] * 32;
        unsigned short* auxk = aux + pxOff[si] * 8;

        if (si == 0)
            dinit_first_k<<<nbp, 256, 0, stream>>>(ebk, D0, Hs, Ws);
        else
            dinit_blend_k<<<nbp, 256, 0, stream>>>(Dprev, ebk, D0, Hs, Ws);

        kfix_k<<<nbp, 256, 0, stream>>>(auxk, cofk, D0, wc, dlk, Hs, Ws);

        float* Dc = D0;
        float* Dn = D1;
        float* fin = (si < 2) ? Dprev : (float*)d_out;
        for (int t = 0; t < 6; t++) {
            float* tgt = (t == 5) ? fin : Dn;
            prop_k<<<nbp, 256, 0, stream>>>(Dc, cofk, tgt, Hs, Ws);
            if (t < 5) { float* tmp = Dc; Dc = Dn; Dn = tmp; }
        }
    }
}